// Round 1
// baseline (896.678 us; speedup 1.0000x reference)
//
#include <hip/hip_runtime.h>
#include <stdint.h>

// ---------------------------------------------------------------------------
// IAM_47794396069954: dual-stream axial (row-wise) cross attention + double
// 3x3 conv heads, b=2, c=64, h=w=320.  All heavy math on bf16 MFMA
// (mfma_f32_16x16x32_bf16), fp32 accumulate.  5 kernels:
//   kpack  : weights -> bf16, conv weights repacked [tap][o][c]
//   kproj  : u/d -> bf16 NCHW copy + [b,h,w,c] transpose + 4x 1x1 proj (MFMA)
//   kattn  : per-(b,h,dir) row attention, exact softmax, no S materialization
//   kconv1 : implicit-GEMM 3x3 over concat(128ch) + ReLU -> mid [b,h,w,c] bf16
//   kconv2 : implicit-GEMM 3x3 (64ch) -> fp32 NCHW into d_out
// MFMA 16x16x32 layouts (verified per guide):
//   A[m][k]: m=lane&15, k=(lane>>4)*8+j ;  B[k][n]: n=lane&15, k=(lane>>4)*8+j
//   C/D    : col=lane&15, row=(lane>>4)*4+reg
// ---------------------------------------------------------------------------

typedef __bf16 bf16;
typedef __bf16 bf16x8 __attribute__((ext_vector_type(8)));
typedef float  f32x4  __attribute__((ext_vector_type(4)));

#define MFMA(a, b, c) __builtin_amdgcn_mfma_f32_16x16x32_bf16((a), (b), (c), 0, 0, 0)

static constexpr int    HWc  = 320 * 320;      // 102400
static constexpr int    CHW  = 64 * HWc;       // 6553600
static constexpr size_t NE   = 2ull * CHW;     // 13107200 elements per tensor

// workspace layout (bf16 elements)
static constexpr size_t OFF_UBF  = 0;          // u bf16 NCHW (attn V)
static constexpr size_t OFF_DBF  = NE;         // d bf16 NCHW (attn V)
static constexpr size_t OFF_UT   = 2 * NE;     // u  [b,h,w,c]
static constexpr size_t OFF_DT   = 3 * NE;     // d  [b,h,w,c]
static constexpr size_t OFF_QUD  = 4 * NE;     // u1 [b,h,w,c]; later mid_u
static constexpr size_t OFF_KUD  = 5 * NE;     // d2
static constexpr size_t OFF_QDU  = 6 * NE;     // d1 ; later mid_d
static constexpr size_t OFF_KDU  = 7 * NE;     // u2
static constexpr size_t OFF_BUFD = 8 * NE;     // buffer_d [b,h,w,c]
static constexpr size_t OFF_BUFU = 9 * NE;     // buffer_u [b,h,w,c]
static constexpr size_t OFF_W1A  = 10 * NE;            // [9][64][128]
static constexpr size_t OFF_W2A  = OFF_W1A + 9*64*128;
static constexpr size_t OFF_W1B  = OFF_W2A + 9*64*128; // [9][64][64]
static constexpr size_t OFF_W2B  = OFF_W1B + 9*64*64;
static constexpr size_t OFF_WU1  = OFF_W2B + 9*64*64;  // [64][64]
static constexpr size_t OFF_WU2  = OFF_WU1 + 4096;
static constexpr size_t OFF_WD1  = OFF_WU2 + 4096;
static constexpr size_t OFF_WD2  = OFF_WD1 + 4096;

// ---------------------------------------------------------------------------
__global__ __launch_bounds__(256) void kpack(
    const float* __restrict__ Wu1, const float* __restrict__ Wu2,
    const float* __restrict__ Wd1, const float* __restrict__ Wd2,
    const float* __restrict__ W1a, const float* __restrict__ W1b,
    const float* __restrict__ W2a, const float* __restrict__ W2b,
    bf16* __restrict__ ws) {
  const int t = blockIdx.x * 256 + threadIdx.x;
  if (t < 9 * 64 * 128) {                 // [tap][o][c] <- W[o][c][ky][kx]
    const int c = t & 127, o = (t >> 7) & 63, tap = t >> 13;
    const int src = (o * 128 + c) * 9 + tap;
    ws[OFF_W1A + t] = (bf16)W1a[src];
    ws[OFF_W2A + t] = (bf16)W2a[src];
  }
  if (t < 9 * 64 * 64) {
    const int c = t & 63, o = (t >> 6) & 63, tap = t >> 12;
    const int src = (o * 64 + c) * 9 + tap;
    ws[OFF_W1B + t] = (bf16)W1b[src];
    ws[OFF_W2B + t] = (bf16)W2b[src];
  }
  if (t < 4096) {
    ws[OFF_WU1 + t] = (bf16)Wu1[t];
    ws[OFF_WU2 + t] = (bf16)Wu2[t];
    ws[OFF_WD1 + t] = (bf16)Wd1[t];
    ws[OFF_WD2 + t] = (bf16)Wd2[t];
  }
}

// ---------------------------------------------------------------------------
// grid (5, 640, 2): x = 64-px tile, y = b*320+h, z = stream (0=u,1=d)
__global__ __launch_bounds__(256) void kproj(const float* __restrict__ u,
                                             const float* __restrict__ d,
                                             bf16* __restrict__ ws) {
  __shared__ float ut[64][68];        // [x][c], stride 68 -> 272B rows (16B ok)
  __shared__ float stg[4][16][68];    // per-wave transpose stage
  const int s   = blockIdx.z;
  const int by  = blockIdx.y;               // b*320 + y
  const int b   = by / 320;
  const int y   = by % 320;
  const int x0  = blockIdx.x * 64;
  const int tid = threadIdx.x;
  const int lane = tid & 63, wv = tid >> 6;
  const int l15 = lane & 15, q4 = lane >> 4;

  const float* src = s ? d : u;
  const bf16* Wq = ws + (s ? OFF_WD1 : OFF_WU1);   // u1 / d1
  const bf16* Wk = ws + (s ? OFF_WD2 : OFF_WU2);   // u2 / d2
  bf16* xbf = ws + (s ? OFF_DBF : OFF_UBF);
  bf16* xt  = ws + (s ? OFF_DT  : OFF_UT);
  bf16* qo  = ws + (s ? OFF_QDU : OFF_QUD);        // u1->q_ud, d1->q_du
  bf16* ko  = ws + (s ? OFF_KUD : OFF_KDU);        // u2->k_du, d2->k_ud

  // phase 1: coalesced load, bf16 NCHW copy, LDS transpose stage
  {
    const int xl = lane;
    const int cb = wv * 16;
#pragma unroll
    for (int i = 0; i < 16; ++i) {
      const int c = cb + i;
      const size_t g = (size_t)(b * 64 + c) * HWc + (size_t)y * 320 + x0 + xl;
      const float v = src[g];
      xbf[g] = (bf16)v;
      ut[xl][c] = v;
    }
  }
  __syncthreads();

  // phase 1b: [b,h,w,c] transpose store
  {
    const int xl = tid >> 2;
    const int cc = (tid & 3) * 16;
    bf16x8 v0, v1;
#pragma unroll
    for (int j = 0; j < 8; ++j) {
      v0[j] = (bf16)ut[xl][cc + j];
      v1[j] = (bf16)ut[xl][cc + 8 + j];
    }
    bf16* p = xt + ((size_t)by * 320 + x0 + xl) * 64 + cc;
    *(bf16x8*)p = v0;
    *(bf16x8*)(p + 8) = v1;
  }

  // phase 2: 1x1 projections.  wave wv handles x-subtile wv*16..+15
  bf16x8 a[2];
#pragma unroll
  for (int ks = 0; ks < 2; ++ks) {
    const int xl = wv * 16 + l15;
    const int c0 = ks * 32 + q4 * 8;
#pragma unroll
    for (int j = 0; j < 8; ++j) a[ks][j] = (bf16)ut[xl][c0 + j];
  }
  const f32x4 zero4 = {0.f, 0.f, 0.f, 0.f};
  f32x4 acc[8];
#pragma unroll
  for (int i = 0; i < 8; ++i) acc[i] = zero4;
#pragma unroll
  for (int ks = 0; ks < 2; ++ks) {
#pragma unroll
    for (int ot = 0; ot < 8; ++ot) {
      const bf16* Wm = (ot < 4) ? Wq : Wk;
      const int o = (ot & 3) * 16 + l15;
      const bf16x8 bw = *(const bf16x8*)(Wm + o * 64 + ks * 32 + q4 * 8);
      acc[ot] = MFMA(a[ks], bw, acc[ot]);
    }
  }
  // epilogue: two passes (q then k), per-wave LDS transpose, 32B stores
#pragma unroll
  for (int pass = 0; pass < 2; ++pass) {
    bf16* dst = pass ? ko : qo;
#pragma unroll
    for (int ot = 0; ot < 4; ++ot)
#pragma unroll
      for (int r = 0; r < 4; ++r)
        stg[wv][q4 * 4 + r][ot * 16 + l15] = acc[pass * 4 + ot][r];
    bf16x8 v0, v1;
    const int cc = q4 * 16;
#pragma unroll
    for (int j = 0; j < 8; ++j) {
      v0[j] = (bf16)stg[wv][l15][cc + j];
      v1[j] = (bf16)stg[wv][l15][cc + 8 + j];
    }
    bf16* p = dst + ((size_t)by * 320 + x0 + wv * 16 + l15) * 64 + cc;
    *(bf16x8*)p = v0;
    *(bf16x8*)(p + 8) = v1;
  }
}

// ---------------------------------------------------------------------------
// grid (640, 2): x = b*320+h, y = direction (0: u->d, Q=u1 K=d2 V=d -> buf_d)
__global__ __launch_bounds__(256) void kattn(bf16* __restrict__ ws) {
  __shared__ __attribute__((aligned(16))) bf16 pch[4][16][72];  // P chunk
  __shared__ float ost[4][16][68];                              // O transpose
  const int dir = blockIdx.y;
  const int bh  = blockIdx.x;
  const int tid = threadIdx.x;
  const int lane = tid & 63, wv = tid >> 6;
  const int l15 = lane & 15, q4 = lane >> 4;

  const bf16* Q = ws + (dir ? OFF_QDU : OFF_QUD) + (size_t)bh * 320 * 64;
  const bf16* K = ws + (dir ? OFF_KDU : OFF_KUD) + (size_t)bh * 320 * 64;
  const bf16* V = ws + (dir ? OFF_UBF : OFF_DBF) + (size_t)(bh / 320) * CHW
                + (size_t)(bh % 320) * 320;
  bf16* O = ws + (dir ? OFF_BUFU : OFF_BUFD) + (size_t)bh * 320 * 64;

  const f32x4 zero4 = {0.f, 0.f, 0.f, 0.f};
  for (int t5 = 0; t5 < 5; ++t5) {
    const int wq0 = (t5 * 4 + wv) * 16;
    const bf16x8 a0 = *(const bf16x8*)(Q + (size_t)(wq0 + l15) * 64 + q4 * 8);
    const bf16x8 a1 = *(const bf16x8*)(Q + (size_t)(wq0 + l15) * 64 + 32 + q4 * 8);
    f32x4 sacc[20];
#pragma unroll
    for (int kt = 0; kt < 20; ++kt) sacc[kt] = zero4;
#pragma unroll
    for (int kt = 0; kt < 20; ++kt) {
      const bf16* kp = K + (size_t)(kt * 16 + l15) * 64 + q4 * 8;
      const bf16x8 b0 = *(const bf16x8*)kp;
      const bf16x8 b1 = *(const bf16x8*)(kp + 32);
      sacc[kt] = MFMA(a0, b0, sacc[kt]);
      sacc[kt] = MFMA(a1, b1, sacc[kt]);
    }
    // exact softmax over the 320-wide row; row wq = q4*4+r lives in this quad
    float mx[4] = {-3.0e38f, -3.0e38f, -3.0e38f, -3.0e38f};
#pragma unroll
    for (int kt = 0; kt < 20; ++kt)
#pragma unroll
      for (int r = 0; r < 4; ++r) mx[r] = fmaxf(mx[r], sacc[kt][r]);
#pragma unroll
    for (int off = 1; off < 16; off <<= 1)
#pragma unroll
      for (int r = 0; r < 4; ++r) mx[r] = fmaxf(mx[r], __shfl_xor(mx[r], off));
    float sm[4] = {0.f, 0.f, 0.f, 0.f};
#pragma unroll
    for (int kt = 0; kt < 20; ++kt)
#pragma unroll
      for (int r = 0; r < 4; ++r) {
        const float e = __expf(sacc[kt][r] - mx[r]);
        sacc[kt][r] = e;
        sm[r] += e;
      }
#pragma unroll
    for (int off = 1; off < 16; off <<= 1)
#pragma unroll
      for (int r = 0; r < 4; ++r) sm[r] += __shfl_xor(sm[r], off);
    float inv[4];
#pragma unroll
    for (int r = 0; r < 4; ++r) inv[r] = 1.f / sm[r];

    // PV: chunks of 64 v; P goes C-layout -> LDS -> A-layout
    f32x4 oac[4];
#pragma unroll
    for (int ct = 0; ct < 4; ++ct) oac[ct] = zero4;
#pragma unroll
    for (int ch = 0; ch < 5; ++ch) {
#pragma unroll
      for (int j = 0; j < 4; ++j) {
        const int kt = ch * 4 + j;
#pragma unroll
        for (int r = 0; r < 4; ++r)
          pch[wv][q4 * 4 + r][j * 16 + l15] = (bf16)(sacc[kt][r] * inv[r]);
      }
      const bf16x8 p0 = *(const bf16x8*)&pch[wv][l15][q4 * 8];
      const bf16x8 p1 = *(const bf16x8*)&pch[wv][l15][32 + q4 * 8];
#pragma unroll
      for (int ct = 0; ct < 4; ++ct) {
        const bf16* vp = V + (size_t)(ct * 16 + l15) * HWc + ch * 64 + q4 * 8;
        const bf16x8 v0 = *(const bf16x8*)vp;
        const bf16x8 v1 = *(const bf16x8*)(vp + 32);
        oac[ct] = MFMA(p0, v0, oac[ct]);
        oac[ct] = MFMA(p1, v1, oac[ct]);
      }
    }
    // epilogue: O[wq][c] -> [b,h,w,c] bf16 via per-wave LDS transpose
#pragma unroll
    for (int ct = 0; ct < 4; ++ct)
#pragma unroll
      for (int r = 0; r < 4; ++r)
        ost[wv][q4 * 4 + r][ct * 16 + l15] = oac[ct][r];
    bf16x8 w0, w1;
    const int cc = q4 * 16;
#pragma unroll
    for (int j = 0; j < 8; ++j) {
      w0[j] = (bf16)ost[wv][l15][cc + j];
      w1[j] = (bf16)ost[wv][l15][cc + 8 + j];
    }
    bf16* p = O + (size_t)(wq0 + l15) * 64 + cc;
    *(bf16x8*)p = w0;
    *(bf16x8*)(p + 8) = w1;
  }
}

// ---------------------------------------------------------------------------
// grid (5, 80, 4): x = 64-px tile, y = 4-row group (wave=row), z = s*2+b
__global__ __launch_bounds__(256) void kconv1(bf16* __restrict__ ws) {
  __shared__ float ost[4][16][68];
  const int s = blockIdx.z >> 1, b = blockIdx.z & 1;
  const int x0 = blockIdx.x * 64;
  const int tid = threadIdx.x;
  const int lane = tid & 63, wv = tid >> 6;
  const int l15 = lane & 15, q4 = lane >> 4;
  const int y = blockIdx.y * 4 + wv;
  const bf16* X1 = ws + (s ? OFF_DT : OFF_UT) + (size_t)b * CHW;
  const bf16* X2 = ws + (s ? OFF_BUFU : OFF_BUFD) + (size_t)b * CHW;
  const bf16* Wg = ws + (s ? OFF_W2A : OFF_W1A);
  bf16* Mo = ws + (s ? OFF_QDU : OFF_QUD) + (size_t)b * CHW;  // mid aliases q

  const f32x4 zero4 = {0.f, 0.f, 0.f, 0.f};
  f32x4 acc[4][4];
#pragma unroll
  for (int i = 0; i < 4; ++i)
#pragma unroll
    for (int j = 0; j < 4; ++j) acc[i][j] = zero4;

  for (int ky = 0; ky < 3; ++ky) {
    const int yy = y + ky - 1;
    const bool yok = (unsigned)yy < 320u;
    for (int kx = 0; kx < 3; ++kx) {
      const int tap = ky * 3 + kx;
#pragma unroll
      for (int ks = 0; ks < 4; ++ks) {               // 128 concat channels
        const bf16* Xs = (ks < 2) ? X1 : X2;
        const int ci = (ks & 1) * 32 + q4 * 8;
        bf16x8 bw[4];
#pragma unroll
        for (int ot = 0; ot < 4; ++ot)
          bw[ot] = *(const bf16x8*)(Wg + ((size_t)tap * 64 + ot * 16 + l15) * 128
                                    + ks * 32 + q4 * 8);
#pragma unroll
        for (int xt = 0; xt < 4; ++xt) {
          const int xx = x0 + xt * 16 + l15 + kx - 1;
          bf16x8 af;
#pragma unroll
          for (int j = 0; j < 8; ++j) af[j] = (bf16)0.f;
          if (yok && (unsigned)xx < 320u)
            af = *(const bf16x8*)(Xs + ((size_t)yy * 320 + xx) * 64 + ci);
#pragma unroll
          for (int ot = 0; ot < 4; ++ot)
            acc[xt][ot] = MFMA(af, bw[ot], acc[xt][ot]);
        }
      }
    }
  }
  // ReLU + transpose epilogue -> mid [b,h,w,c] bf16
#pragma unroll
  for (int xt = 0; xt < 4; ++xt) {
#pragma unroll
    for (int ot = 0; ot < 4; ++ot)
#pragma unroll
      for (int r = 0; r < 4; ++r)
        ost[wv][q4 * 4 + r][ot * 16 + l15] = fmaxf(acc[xt][ot][r], 0.f);
    bf16x8 w0, w1;
    const int cc = q4 * 16;
#pragma unroll
    for (int j = 0; j < 8; ++j) {
      w0[j] = (bf16)ost[wv][l15][cc + j];
      w1[j] = (bf16)ost[wv][l15][cc + 8 + j];
    }
    bf16* p = Mo + ((size_t)y * 320 + x0 + xt * 16 + l15) * 64 + cc;
    *(bf16x8*)p = w0;
    *(bf16x8*)(p + 8) = w1;
  }
}

// ---------------------------------------------------------------------------
// grid (5, 80, 4): final 3x3 conv, fp32 NCHW output straight from C-layout
__global__ __launch_bounds__(256) void kconv2(const bf16* __restrict__ ws,
                                              float* __restrict__ out) {
  const int s = blockIdx.z >> 1, b = blockIdx.z & 1;
  const int x0 = blockIdx.x * 64;
  const int tid = threadIdx.x;
  const int lane = tid & 63, wv = tid >> 6;
  const int l15 = lane & 15, q4 = lane >> 4;
  const int y = blockIdx.y * 4 + wv;
  const bf16* X  = ws + (s ? OFF_QDU : OFF_QUD) + (size_t)b * CHW;  // mid
  const bf16* Wg = ws + (s ? OFF_W2B : OFF_W1B);
  float* O = out + (size_t)s * NE + (size_t)b * CHW;

  const f32x4 zero4 = {0.f, 0.f, 0.f, 0.f};
  f32x4 acc[4][4];
#pragma unroll
  for (int i = 0; i < 4; ++i)
#pragma unroll
    for (int j = 0; j < 4; ++j) acc[i][j] = zero4;

  for (int ky = 0; ky < 3; ++ky) {
    const int yy = y + ky - 1;
    const bool yok = (unsigned)yy < 320u;
    for (int kx = 0; kx < 3; ++kx) {
      const int tap = ky * 3 + kx;
#pragma unroll
      for (int ks = 0; ks < 2; ++ks) {
        bf16x8 bw[4];
#pragma unroll
        for (int ot = 0; ot < 4; ++ot)
          bw[ot] = *(const bf16x8*)(Wg + ((size_t)tap * 64 + ot * 16 + l15) * 64
                                    + ks * 32 + q4 * 8);
#pragma unroll
        for (int xt = 0; xt < 4; ++xt) {
          const int xx = x0 + xt * 16 + l15 + kx - 1;
          bf16x8 af;
#pragma unroll
          for (int j = 0; j < 8; ++j) af[j] = (bf16)0.f;
          if (yok && (unsigned)xx < 320u)
            af = *(const bf16x8*)(X + ((size_t)yy * 320 + xx) * 64 + ks * 32 + q4 * 8);
#pragma unroll
          for (int ot = 0; ot < 4; ++ot)
            acc[xt][ot] = MFMA(af, bw[ot], acc[xt][ot]);
        }
      }
    }
  }
#pragma unroll
  for (int xt = 0; xt < 4; ++xt)
#pragma unroll
    for (int ot = 0; ot < 4; ++ot) {
      const int o = ot * 16 + l15;
      float* p = O + (size_t)o * HWc + (size_t)y * 320 + x0 + xt * 16 + q4 * 4;
      *(f32x4*)p = acc[xt][ot];
    }
}

// ---------------------------------------------------------------------------
extern "C" void kernel_launch(void* const* d_in, const int* in_sizes, int n_in,
                              void* d_out, int out_size, void* d_ws, size_t ws_size,
                              hipStream_t stream) {
  const float* u   = (const float*)d_in[0];
  const float* d   = (const float*)d_in[1];
  const float* Wu1 = (const float*)d_in[2];
  const float* Wu2 = (const float*)d_in[3];
  const float* Wd1 = (const float*)d_in[4];
  const float* Wd2 = (const float*)d_in[5];
  const float* W1a = (const float*)d_in[6];
  const float* W1b = (const float*)d_in[7];
  const float* W2a = (const float*)d_in[8];
  const float* W2b = (const float*)d_in[9];
  bf16* ws = (bf16*)d_ws;
  float* out = (float*)d_out;

  kpack<<<dim3((9 * 64 * 128 + 255) / 256), 256, 0, stream>>>(
      Wu1, Wu2, Wd1, Wd2, W1a, W1b, W2a, W2b, ws);
  kproj<<<dim3(5, 640, 2), 256, 0, stream>>>(u, d, ws);
  kattn<<<dim3(640, 2), 256, 0, stream>>>(ws);
  kconv1<<<dim3(5, 80, 4), 256, 0, stream>>>(ws);
  kconv2<<<dim3(5, 80, 4), 256, 0, stream>>>(ws, out);
}

// Round 2
// 771.414 us; speedup vs baseline: 1.1624x; 1.1624x over previous
//
#include <hip/hip_runtime.h>
#include <stdint.h>

// ---------------------------------------------------------------------------
// IAM_47794396069954: dual-stream axial (row-wise) cross attention + double
// 3x3 conv heads, b=2, c=64, h=w=320.  All heavy math on bf16 MFMA
// (mfma_f32_16x16x32_bf16), fp32 accumulate.  5 kernels:
//   kpack  : weights -> bf16, conv weights repacked [tap][o][c]
//   kproj  : u/d -> bf16 NCHW copy + [b,h,w,c] transpose + 4x 1x1 proj (MFMA)
//   kattn  : per-(b,h,dir) row attention, exact softmax, no S materialization
//   kconv1 : LDS-staged implicit-GEMM 3x3 (concat 128ch) + ReLU -> mid bf16
//   kconv2 : LDS-staged implicit-GEMM 3x3 (64ch) -> fp32 NCHW into d_out
// MFMA 16x16x32 layouts:
//   A[m][k]: m=lane&15, k=(lane>>4)*8+j ;  B[k][n]: n=lane&15, k=(lane>>4)*8+j
//   C/D    : col=lane&15, row=(lane>>4)*4+reg
// ---------------------------------------------------------------------------

typedef __bf16 bf16;
typedef __bf16 bf16x8 __attribute__((ext_vector_type(8)));
typedef float  f32x4  __attribute__((ext_vector_type(4)));

#define MFMA(a, b, c) __builtin_amdgcn_mfma_f32_16x16x32_bf16((a), (b), (c), 0, 0, 0)

static constexpr int    HWc  = 320 * 320;      // 102400
static constexpr int    CHW  = 64 * HWc;       // 6553600
static constexpr size_t NE   = 2ull * CHW;     // 13107200 elements per tensor

// workspace layout (bf16 elements)
static constexpr size_t OFF_UBF  = 0;          // u bf16 NCHW (attn V)
static constexpr size_t OFF_DBF  = NE;         // d bf16 NCHW (attn V)
static constexpr size_t OFF_UT   = 2 * NE;     // u  [b,h,w,c]
static constexpr size_t OFF_DT   = 3 * NE;     // d  [b,h,w,c]
static constexpr size_t OFF_QUD  = 4 * NE;     // u1 [b,h,w,c]; later mid_u
static constexpr size_t OFF_KUD  = 5 * NE;     // d2
static constexpr size_t OFF_QDU  = 6 * NE;     // d1 ; later mid_d
static constexpr size_t OFF_KDU  = 7 * NE;     // u2
static constexpr size_t OFF_BUFD = 8 * NE;     // buffer_d [b,h,w,c]
static constexpr size_t OFF_BUFU = 9 * NE;     // buffer_u [b,h,w,c]
static constexpr size_t OFF_W1A  = 10 * NE;            // [9][64][128]
static constexpr size_t OFF_W2A  = OFF_W1A + 9*64*128;
static constexpr size_t OFF_W1B  = OFF_W2A + 9*64*128; // [9][64][64]
static constexpr size_t OFF_W2B  = OFF_W1B + 9*64*64;
static constexpr size_t OFF_WU1  = OFF_W2B + 9*64*64;  // [64][64]
static constexpr size_t OFF_WU2  = OFF_WU1 + 4096;
static constexpr size_t OFF_WD1  = OFF_WU2 + 4096;
static constexpr size_t OFF_WD2  = OFF_WD1 + 4096;

// ---------------------------------------------------------------------------
__global__ __launch_bounds__(256) void kpack(
    const float* __restrict__ Wu1, const float* __restrict__ Wu2,
    const float* __restrict__ Wd1, const float* __restrict__ Wd2,
    const float* __restrict__ W1a, const float* __restrict__ W1b,
    const float* __restrict__ W2a, const float* __restrict__ W2b,
    bf16* __restrict__ ws) {
  const int t = blockIdx.x * 256 + threadIdx.x;
  if (t < 9 * 64 * 128) {                 // [tap][o][c] <- W[o][c][ky][kx]
    const int c = t & 127, o = (t >> 7) & 63, tap = t >> 13;
    const int src = (o * 128 + c) * 9 + tap;
    ws[OFF_W1A + t] = (bf16)W1a[src];
    ws[OFF_W2A + t] = (bf16)W2a[src];
  }
  if (t < 9 * 64 * 64) {
    const int c = t & 63, o = (t >> 6) & 63, tap = t >> 12;
    const int src = (o * 64 + c) * 9 + tap;
    ws[OFF_W1B + t] = (bf16)W1b[src];
    ws[OFF_W2B + t] = (bf16)W2b[src];
  }
  if (t < 4096) {
    ws[OFF_WU1 + t] = (bf16)Wu1[t];
    ws[OFF_WU2 + t] = (bf16)Wu2[t];
    ws[OFF_WD1 + t] = (bf16)Wd1[t];
    ws[OFF_WD2 + t] = (bf16)Wd2[t];
  }
}

// ---------------------------------------------------------------------------
// grid (5, 640, 2): x = 64-px tile, y = b*320+h, z = stream (0=u,1=d)
__global__ __launch_bounds__(256) void kproj(const float* __restrict__ u,
                                             const float* __restrict__ d,
                                             bf16* __restrict__ ws) {
  __shared__ float ut[64][68];        // [x][c]
  __shared__ float stg[4][16][68];    // per-wave transpose stage
  const int s   = blockIdx.z;
  const int by  = blockIdx.y;               // b*320 + y
  const int b   = by / 320;
  const int y   = by % 320;
  const int x0  = blockIdx.x * 64;
  const int tid = threadIdx.x;
  const int lane = tid & 63, wv = tid >> 6;
  const int l15 = lane & 15, q4 = lane >> 4;

  const float* src = s ? d : u;
  const bf16* Wq = ws + (s ? OFF_WD1 : OFF_WU1);   // u1 / d1
  const bf16* Wk = ws + (s ? OFF_WD2 : OFF_WU2);   // u2 / d2
  bf16* xbf = ws + (s ? OFF_DBF : OFF_UBF);
  bf16* xt  = ws + (s ? OFF_DT  : OFF_UT);
  bf16* qo  = ws + (s ? OFF_QDU : OFF_QUD);        // u1->q_ud, d1->q_du
  bf16* ko  = ws + (s ? OFF_KUD : OFF_KDU);        // u2->k_du, d2->k_ud

  // phase 1: coalesced load, bf16 NCHW copy, LDS transpose stage
  {
    const int xl = lane;
    const int cb = wv * 16;
#pragma unroll
    for (int i = 0; i < 16; ++i) {
      const int c = cb + i;
      const size_t g = (size_t)(b * 64 + c) * HWc + (size_t)y * 320 + x0 + xl;
      const float v = src[g];
      xbf[g] = (bf16)v;
      ut[xl][c] = v;
    }
  }
  __syncthreads();

  // phase 1b: [b,h,w,c] transpose store
  {
    const int xl = tid >> 2;
    const int cc = (tid & 3) * 16;
    bf16x8 v0, v1;
#pragma unroll
    for (int j = 0; j < 8; ++j) {
      v0[j] = (bf16)ut[xl][cc + j];
      v1[j] = (bf16)ut[xl][cc + 8 + j];
    }
    bf16* p = xt + ((size_t)by * 320 + x0 + xl) * 64 + cc;
    *(bf16x8*)p = v0;
    *(bf16x8*)(p + 8) = v1;
  }

  // phase 2: 1x1 projections.  wave wv handles x-subtile wv*16..+15
  bf16x8 a[2];
#pragma unroll
  for (int ks = 0; ks < 2; ++ks) {
    const int xl = wv * 16 + l15;
    const int c0 = ks * 32 + q4 * 8;
#pragma unroll
    for (int j = 0; j < 8; ++j) a[ks][j] = (bf16)ut[xl][c0 + j];
  }
  const f32x4 zero4 = {0.f, 0.f, 0.f, 0.f};
  f32x4 acc[8];
#pragma unroll
  for (int i = 0; i < 8; ++i) acc[i] = zero4;
#pragma unroll
  for (int ks = 0; ks < 2; ++ks) {
#pragma unroll
    for (int ot = 0; ot < 8; ++ot) {
      const bf16* Wm = (ot < 4) ? Wq : Wk;
      const int o = (ot & 3) * 16 + l15;
      const bf16x8 bw = *(const bf16x8*)(Wm + o * 64 + ks * 32 + q4 * 8);
      acc[ot] = MFMA(a[ks], bw, acc[ot]);
    }
  }
  // epilogue: two passes (q then k), per-wave LDS transpose, 32B stores
#pragma unroll
  for (int pass = 0; pass < 2; ++pass) {
    bf16* dst = pass ? ko : qo;
#pragma unroll
    for (int ot = 0; ot < 4; ++ot)
#pragma unroll
      for (int r = 0; r < 4; ++r)
        stg[wv][q4 * 4 + r][ot * 16 + l15] = acc[pass * 4 + ot][r];
    bf16x8 v0, v1;
    const int cc = q4 * 16;
#pragma unroll
    for (int j = 0; j < 8; ++j) {
      v0[j] = (bf16)stg[wv][l15][cc + j];
      v1[j] = (bf16)stg[wv][l15][cc + 8 + j];
    }
    bf16* p = dst + ((size_t)by * 320 + x0 + wv * 16 + l15) * 64 + cc;
    *(bf16x8*)p = v0;
    *(bf16x8*)(p + 8) = v1;
  }
}

// ---------------------------------------------------------------------------
// grid (640, 2): x = b*320+h, y = direction (0: u->d, Q=u1 K=d2 V=d -> buf_d)
__global__ __launch_bounds__(256) void kattn(bf16* __restrict__ ws) {
  __shared__ __attribute__((aligned(16))) bf16 pch[4][16][72];  // P chunk
  __shared__ float ost[4][16][68];                              // O transpose
  const int dir = blockIdx.y;
  const int bh  = blockIdx.x;
  const int tid = threadIdx.x;
  const int lane = tid & 63, wv = tid >> 6;
  const int l15 = lane & 15, q4 = lane >> 4;

  const bf16* Q = ws + (dir ? OFF_QDU : OFF_QUD) + (size_t)bh * 320 * 64;
  const bf16* K = ws + (dir ? OFF_KDU : OFF_KUD) + (size_t)bh * 320 * 64;
  const bf16* V = ws + (dir ? OFF_UBF : OFF_DBF) + (size_t)(bh / 320) * CHW
                + (size_t)(bh % 320) * 320;
  bf16* O = ws + (dir ? OFF_BUFU : OFF_BUFD) + (size_t)bh * 320 * 64;

  const f32x4 zero4 = {0.f, 0.f, 0.f, 0.f};
  for (int t5 = 0; t5 < 5; ++t5) {
    const int wq0 = (t5 * 4 + wv) * 16;
    const bf16x8 a0 = *(const bf16x8*)(Q + (size_t)(wq0 + l15) * 64 + q4 * 8);
    const bf16x8 a1 = *(const bf16x8*)(Q + (size_t)(wq0 + l15) * 64 + 32 + q4 * 8);
    f32x4 sacc[20];
#pragma unroll
    for (int kt = 0; kt < 20; ++kt) sacc[kt] = zero4;
#pragma unroll
    for (int kt = 0; kt < 20; ++kt) {
      const bf16* kp = K + (size_t)(kt * 16 + l15) * 64 + q4 * 8;
      const bf16x8 b0 = *(const bf16x8*)kp;
      const bf16x8 b1 = *(const bf16x8*)(kp + 32);
      sacc[kt] = MFMA(a0, b0, sacc[kt]);
      sacc[kt] = MFMA(a1, b1, sacc[kt]);
    }
    // exact softmax over the 320-wide row; row wq = q4*4+r lives in this quad
    float mx[4] = {-3.0e38f, -3.0e38f, -3.0e38f, -3.0e38f};
#pragma unroll
    for (int kt = 0; kt < 20; ++kt)
#pragma unroll
      for (int r = 0; r < 4; ++r) mx[r] = fmaxf(mx[r], sacc[kt][r]);
#pragma unroll
    for (int off = 1; off < 16; off <<= 1)
#pragma unroll
      for (int r = 0; r < 4; ++r) mx[r] = fmaxf(mx[r], __shfl_xor(mx[r], off));
    float sm[4] = {0.f, 0.f, 0.f, 0.f};
#pragma unroll
    for (int kt = 0; kt < 20; ++kt)
#pragma unroll
      for (int r = 0; r < 4; ++r) {
        const float e = __expf(sacc[kt][r] - mx[r]);
        sacc[kt][r] = e;
        sm[r] += e;
      }
#pragma unroll
    for (int off = 1; off < 16; off <<= 1)
#pragma unroll
      for (int r = 0; r < 4; ++r) sm[r] += __shfl_xor(sm[r], off);
    float inv[4];
#pragma unroll
    for (int r = 0; r < 4; ++r) inv[r] = 1.f / sm[r];

    // PV: chunks of 64 v; P goes C-layout -> LDS -> A-layout
    f32x4 oac[4];
#pragma unroll
    for (int ct = 0; ct < 4; ++ct) oac[ct] = zero4;
#pragma unroll
    for (int ch = 0; ch < 5; ++ch) {
#pragma unroll
      for (int j = 0; j < 4; ++j) {
        const int kt = ch * 4 + j;
#pragma unroll
        for (int r = 0; r < 4; ++r)
          pch[wv][q4 * 4 + r][j * 16 + l15] = (bf16)(sacc[kt][r] * inv[r]);
      }
      const bf16x8 p0 = *(const bf16x8*)&pch[wv][l15][q4 * 8];
      const bf16x8 p1 = *(const bf16x8*)&pch[wv][l15][32 + q4 * 8];
#pragma unroll
      for (int ct = 0; ct < 4; ++ct) {
        const bf16* vp = V + (size_t)(ct * 16 + l15) * HWc + ch * 64 + q4 * 8;
        const bf16x8 v0 = *(const bf16x8*)vp;
        const bf16x8 v1 = *(const bf16x8*)(vp + 32);
        oac[ct] = MFMA(p0, v0, oac[ct]);
        oac[ct] = MFMA(p1, v1, oac[ct]);
      }
    }
    // epilogue: O[wq][c] -> [b,h,w,c] bf16 via per-wave LDS transpose
#pragma unroll
    for (int ct = 0; ct < 4; ++ct)
#pragma unroll
      for (int r = 0; r < 4; ++r)
        ost[wv][q4 * 4 + r][ct * 16 + l15] = oac[ct][r];
    bf16x8 w0, w1;
    const int cc = q4 * 16;
#pragma unroll
    for (int j = 0; j < 8; ++j) {
      w0[j] = (bf16)ost[wv][l15][cc + j];
      w1[j] = (bf16)ost[wv][l15][cc + 8 + j];
    }
    bf16* p = O + (size_t)(wq0 + l15) * 64 + cc;
    *(bf16x8*)p = w0;
    *(bf16x8*)(p + 8) = w1;
  }
}

// ---------------------------------------------------------------------------
// kconv1 v2: LDS-staged implicit GEMM.  grid (10, 40, 4): 32-px x-tile,
// 8-row y-tile, z = s*2+b.  4 waves; wave wv owns rows y0+wv*2+{0,1}.
// Per concat-half t: stage input slab [10 rows][8 ch-chunks][34 px] (43.5 KB)
// then 9 taps x 2 ks: A from LDS (ds_read_b128), B from global (L1/L2-hot),
// 16 MFMA on 16 persistent accumulators.
__global__ __launch_bounds__(256, 3) void kconv1(bf16* __restrict__ ws) {
  __shared__ __attribute__((aligned(16))) bf16 xs[10 * 8 * 34 * 8];  // 43520 B
  __shared__ __attribute__((aligned(16))) bf16 stg[4][16][72];       //  9216 B
  const int s = blockIdx.z >> 1, b = blockIdx.z & 1;
  const int x0 = blockIdx.x * 32;
  const int y0 = blockIdx.y * 8;
  const int tid = threadIdx.x;
  const int lane = tid & 63, wv = tid >> 6;
  const int l15 = lane & 15, q4 = lane >> 4;

  const bf16* X1 = ws + (s ? OFF_DT : OFF_UT) + (size_t)b * CHW;
  const bf16* X2 = ws + (s ? OFF_BUFU : OFF_BUFD) + (size_t)b * CHW;
  const bf16* Wg = ws + (s ? OFF_W2A : OFF_W1A);
  bf16* Mo = ws + (s ? OFF_QDU : OFF_QUD) + (size_t)b * CHW;  // mid aliases q

  const f32x4 zero4 = {0.f, 0.f, 0.f, 0.f};
  f32x4 acc[2][2][4];
#pragma unroll
  for (int r = 0; r < 2; ++r)
#pragma unroll
    for (int xt = 0; xt < 2; ++xt)
#pragma unroll
      for (int ot = 0; ot < 4; ++ot) acc[r][xt][ot] = zero4;

  for (int t = 0; t < 2; ++t) {
    __syncthreads();                       // LDS reuse guard (no-op 1st iter)
    const bf16* Xt = t ? X2 : X1;
    for (int i = tid; i < 2720; i += 256) {
      const int row = i / 272, rem = i % 272;
      const int px = rem >> 3, chunk = rem & 7;
      const int yy = y0 - 1 + row, xx = x0 - 1 + px;
      bf16x8 v;
#pragma unroll
      for (int j = 0; j < 8; ++j) v[j] = (bf16)0.f;
      if ((unsigned)yy < 320u && (unsigned)xx < 320u)
        v = *(const bf16x8*)(Xt + ((size_t)yy * 320 + xx) * 64 + chunk * 8);
      *(bf16x8*)(xs + (((row * 8 + chunk) * 34 + px) * 8)) = v;
    }
    __syncthreads();
#pragma unroll
    for (int ky = 0; ky < 3; ++ky)
#pragma unroll
      for (int kx = 0; kx < 3; ++kx)
#pragma unroll
        for (int ks = 0; ks < 2; ++ks) {
          const int tap = ky * 3 + kx;
          bf16x8 bw[4];
#pragma unroll
          for (int ot = 0; ot < 4; ++ot)
            bw[ot] = *(const bf16x8*)(Wg + ((size_t)tap * 64 + ot * 16 + l15) * 128
                                      + t * 64 + ks * 32 + q4 * 8);
          bf16x8 af[2][2];
#pragma unroll
          for (int r = 0; r < 2; ++r)
#pragma unroll
            for (int xt = 0; xt < 2; ++xt)
              af[r][xt] = *(const bf16x8*)(xs + (((wv * 2 + r + ky) * 8 + ks * 4 + q4) * 34
                                                 + xt * 16 + l15 + kx) * 8);
#pragma unroll
          for (int r = 0; r < 2; ++r)
#pragma unroll
            for (int xt = 0; xt < 2; ++xt)
#pragma unroll
              for (int ot = 0; ot < 4; ++ot)
                acc[r][xt][ot] = MFMA(af[r][xt], bw[ot], acc[r][xt][ot]);
        }
  }
  // ReLU + per-wave transpose epilogue -> mid [b,h,w,c] bf16
#pragma unroll
  for (int r = 0; r < 2; ++r)
#pragma unroll
    for (int xt = 0; xt < 2; ++xt) {
#pragma unroll
      for (int ot = 0; ot < 4; ++ot)
#pragma unroll
        for (int rr = 0; rr < 4; ++rr)
          stg[wv][q4 * 4 + rr][ot * 16 + l15] = (bf16)fmaxf(acc[r][xt][ot][rr], 0.f);
      __builtin_amdgcn_s_waitcnt(0);       // lgkm drain before re-read
      bf16x8 w0, w1;
      const int cc = q4 * 16;
#pragma unroll
      for (int j = 0; j < 8; ++j) {
        w0[j] = stg[wv][l15][cc + j];
        w1[j] = stg[wv][l15][cc + 8 + j];
      }
      const int y = y0 + wv * 2 + r;
      bf16* p = Mo + ((size_t)y * 320 + x0 + xt * 16 + l15) * 64 + cc;
      *(bf16x8*)p = w0;
      *(bf16x8*)(p + 8) = w1;
    }
}

// ---------------------------------------------------------------------------
// kconv2 v2: same skeleton, single 64-ch tensor (K=576), fp32 NCHW output
// straight from C-layout.  grid (10, 40, 4).
__global__ __launch_bounds__(256, 3) void kconv2(const bf16* __restrict__ ws,
                                                 float* __restrict__ out) {
  __shared__ __attribute__((aligned(16))) bf16 xs[10 * 8 * 34 * 8];  // 43520 B
  const int s = blockIdx.z >> 1, b = blockIdx.z & 1;
  const int x0 = blockIdx.x * 32;
  const int y0 = blockIdx.y * 8;
  const int tid = threadIdx.x;
  const int lane = tid & 63, wv = tid >> 6;
  const int l15 = lane & 15, q4 = lane >> 4;

  const bf16* X  = ws + (s ? OFF_QDU : OFF_QUD) + (size_t)b * CHW;  // mid
  const bf16* Wg = ws + (s ? OFF_W2B : OFF_W1B);
  float* O = out + (size_t)s * NE + (size_t)b * CHW;

  const f32x4 zero4 = {0.f, 0.f, 0.f, 0.f};
  f32x4 acc[2][2][4];
#pragma unroll
  for (int r = 0; r < 2; ++r)
#pragma unroll
    for (int xt = 0; xt < 2; ++xt)
#pragma unroll
      for (int ot = 0; ot < 4; ++ot) acc[r][xt][ot] = zero4;

  for (int i = tid; i < 2720; i += 256) {
    const int row = i / 272, rem = i % 272;
    const int px = rem >> 3, chunk = rem & 7;
    const int yy = y0 - 1 + row, xx = x0 - 1 + px;
    bf16x8 v;
#pragma unroll
    for (int j = 0; j < 8; ++j) v[j] = (bf16)0.f;
    if ((unsigned)yy < 320u && (unsigned)xx < 320u)
      v = *(const bf16x8*)(X + ((size_t)yy * 320 + xx) * 64 + chunk * 8);
    *(bf16x8*)(xs + (((row * 8 + chunk) * 34 + px) * 8)) = v;
  }
  __syncthreads();
#pragma unroll
  for (int ky = 0; ky < 3; ++ky)
#pragma unroll
    for (int kx = 0; kx < 3; ++kx)
#pragma unroll
      for (int ks = 0; ks < 2; ++ks) {
        const int tap = ky * 3 + kx;
        bf16x8 bw[4];
#pragma unroll
        for (int ot = 0; ot < 4; ++ot)
          bw[ot] = *(const bf16x8*)(Wg + ((size_t)tap * 64 + ot * 16 + l15) * 64
                                    + ks * 32 + q4 * 8);
        bf16x8 af[2][2];
#pragma unroll
        for (int r = 0; r < 2; ++r)
#pragma unroll
          for (int xt = 0; xt < 2; ++xt)
            af[r][xt] = *(const bf16x8*)(xs + (((wv * 2 + r + ky) * 8 + ks * 4 + q4) * 34
                                               + xt * 16 + l15 + kx) * 8);
#pragma unroll
        for (int r = 0; r < 2; ++r)
#pragma unroll
          for (int xt = 0; xt < 2; ++xt)
#pragma unroll
            for (int ot = 0; ot < 4; ++ot)
              acc[r][xt][ot] = MFMA(af[r][xt], bw[ot], acc[r][xt][ot]);
      }
  // fp32 NCHW store: row=(lane>>4)*4+reg (px), col=lane&15 (out ch)
#pragma unroll
  for (int r = 0; r < 2; ++r)
#pragma unroll
    for (int xt = 0; xt < 2; ++xt)
#pragma unroll
      for (int ot = 0; ot < 4; ++ot) {
        const int o = ot * 16 + l15;
        const int y = y0 + wv * 2 + r;
        float* p = O + (size_t)o * HWc + (size_t)y * 320 + x0 + xt * 16 + q4 * 4;
        *(f32x4*)p = acc[r][xt][ot];
      }
}

// ---------------------------------------------------------------------------
extern "C" void kernel_launch(void* const* d_in, const int* in_sizes, int n_in,
                              void* d_out, int out_size, void* d_ws, size_t ws_size,
                              hipStream_t stream) {
  const float* u   = (const float*)d_in[0];
  const float* d   = (const float*)d_in[1];
  const float* Wu1 = (const float*)d_in[2];
  const float* Wu2 = (const float*)d_in[3];
  const float* Wd1 = (const float*)d_in[4];
  const float* Wd2 = (const float*)d_in[5];
  const float* W1a = (const float*)d_in[6];
  const float* W1b = (const float*)d_in[7];
  const float* W2a = (const float*)d_in[8];
  const float* W2b = (const float*)d_in[9];
  bf16* ws = (bf16*)d_ws;
  float* out = (float*)d_out;

  kpack<<<dim3((9 * 64 * 128 + 255) / 256), 256, 0, stream>>>(
      Wu1, Wu2, Wd1, Wd2, W1a, W1b, W2a, W2b, ws);
  kproj<<<dim3(5, 640, 2), 256, 0, stream>>>(u, d, ws);
  kattn<<<dim3(640, 2), 256, 0, stream>>>(ws);
  kconv1<<<dim3(10, 40, 4), 256, 0, stream>>>(ws);
  kconv2<<<dim3(10, 40, 4), 256, 0, stream>>>(ws, out);
}